// Round 4
// baseline (667.261 us; speedup 1.0000x reference)
//
#include <hip/hip_runtime.h>
#include <math.h>

#define RESN  160
#define VOX   4096000          // 160^3
#define YSTR  160
#define ZSTR  25600            // 160*160
#define NPTS  478              // last sample index
#define NRAYS 2048
#define REC   32               // ushorts per voxel record (28 used + 4 pad) = 64B

typedef float f2_u __attribute__((ext_vector_type(2), aligned(4)));

// ============================ transpose kernel ============================
// [28][V] f32  ->  [V][32] bf16 (sigma, 27 rgb-sh, 4 zero pad), 64B/voxel
__global__ __launch_bounds__(256)
void transpose_grid(const float* __restrict__ sig, const float* __restrict__ rgb,
                    unsigned short* __restrict__ rec)
{
    const int v = blockIdx.x * 256 + threadIdx.x;      // grid = 16000 * 256 = VOX
    float vals[32];
    vals[0] = sig[v];
    #pragma unroll
    for (int k = 0; k < 27; ++k) vals[1 + k] = rgb[(size_t)k * VOX + v];
    vals[28] = vals[29] = vals[30] = vals[31] = 0.f;
    unsigned short h[32];
    #pragma unroll
    for (int k = 0; k < 32; ++k) {
        unsigned u = __float_as_uint(vals[k]);
        unsigned r = (u + 0x7FFFu + ((u >> 16) & 1u)) >> 16;   // RNE to bf16
        h[k] = (unsigned short)r;
    }
    uint4* dst = (uint4*)(rec + (size_t)v * REC);
    const uint4* src = (const uint4*)h;
    #pragma unroll
    for (int i = 0; i < 4; ++i) dst[i] = src[i];
}

// ============================ render kernel ============================
__device__ __forceinline__ void bf2(unsigned u, float& lo, float& hi) {
    lo = __uint_as_float(u << 16);
    hi = __uint_as_float(u & 0xFFFF0000u);
}

__global__ __launch_bounds__(256)
void plenoxel_render2(const float* __restrict__ rays_o,
                      const float* __restrict__ rays_d,
                      const unsigned short* __restrict__ rec,
                      float* __restrict__ out)
{
    const int ray  = blockIdx.x;
    const int tid  = threadIdx.x;
    const int wave = tid >> 6;
    const int lane = tid & 63;

    const float ox = rays_o[ray*3+0], oy = rays_o[ray*3+1], oz = rays_o[ray*3+2];
    const float dxr = rays_d[ray*3+0], dyr = rays_d[ray*3+1], dzr = rays_d[ray*3+2];

    const float h = 2.6f * 1.7320508075688772f / 480.0f;

    // start t
    const float ax = (1.3f - ox) / dxr, bx = (-1.3f - ox) / dxr;
    const float ay = (1.3f - oy) / dyr, by = (-1.3f - oy) / dyr;
    const float az = (1.3f - oz) / dzr, bz = (-1.3f - oz) / dzr;
    float start = fmaxf(fmaxf(fminf(ax, bx), fminf(ay, by)), fminf(az, bz));
    start = fminf(fmaxf(start, 0.2f), 6.0f);

    // live sample range (1-voxel margin)
    const float B = 1.3164f;
    const float mx1 = ( B - ox) / dxr, mx0 = (-B - ox) / dxr;
    const float my1 = ( B - oy) / dyr, my0 = (-B - oy) / dyr;
    const float mz1 = ( B - oz) / dzr, mz0 = (-B - oz) / dzr;
    float tl = fmaxf(fmaxf(fminf(mx0, mx1), fminf(my0, my1)), fminf(mz0, mz1));
    float th = fminf(fminf(fmaxf(mx0, mx1), fmaxf(my0, my1)), fmaxf(mz0, mz1));
    tl = fmaxf(tl, start);
    th = fminf(th, fmaf((float)NPTS, h, start));
    int s_lo, s_hi;
    if (th < tl) { s_lo = 0; s_hi = -1; }
    else {
        s_lo = max(0,    (int)floorf((tl - start) / h) - 1);
        s_hi = min(NPTS, (int)ceilf ((th - start) / h) + 1);
    }

    // SH of normalized dir
    const float dsq  = dxr*dxr + dyr*dyr + dzr*dzr;
    const float dinv = rsqrtf(dsq);
    const float dn   = sqrtf(dsq);
    const float X = dxr * dinv, Y = dyr * dinv, Z = dzr * dinv;
    const float shv[9] = {
        0.28209479177387814f,
        -0.4886025119029199f * Y,
         0.4886025119029199f * Z,
        -0.4886025119029199f * X,
         1.0925484305920792f * X * Y,
        -1.0925484305920792f * Y * Z,
         0.31539156525252005f * (2.0f * Z * Z - X * X - Y * Y),
        -1.0925484305920792f * X * Z,
         0.5462742152960396f * (X * X - Y * Y),
    };
    const float dist = h * dn;

    float accR = 0.f, accG = 0.f, accB = 0.f, accL = 0.f;
    float carry = 1.0f;

    const int nlive = s_hi - s_lo + 1;
    if (nlive > 0) {
        const int chunk = (nlive + 3) >> 2;
        const int my_lo = s_lo + wave * chunk;
        const int my_hi = min(my_lo + chunk - 1, s_hi);

        for (int basei = my_lo; basei <= my_hi; basei += 64) {
            const int s = basei + lane;
            float alpha = 0.f, cr = 0.f, cg = 0.f, cb = 0.f;
            if (s <= my_hi) {
                const float t  = fmaf((float)s, h, start);
                const float px = fmaf(dxr, t, ox);
                const float py = fmaf(dyr, t, oy);
                const float pz = fmaf(dzr, t, oz);
                const float fx = fmaf(px, 61.153846153846f, 79.5f);
                const float fy = fmaf(py, 61.153846153846f, 79.5f);
                const float fz = fmaf(pz, 61.153846153846f, 79.5f);
                const float fxf = floorf(fx), fyf = floorf(fy), fzf = floorf(fz);
                const int   x0 = (int)fxf, y0 = (int)fyf, z0 = (int)fzf;
                const float wx1 = fx - fxf, wy1 = fy - fyf, wz1 = fz - fzf;
                const float wx0 = 1.f - wx1, wy0 = 1.f - wy1, wz0 = 1.f - wz1;

                float sv = 0.f, a0 = 0.f, a1 = 0.f, a2 = 0.f;

                if (x0 >= 0 && x0 <= 158 && y0 >= 0 && y0 <= 158 && z0 >= 0 && z0 <= 158) {
                    // interior: 4 corner-pairs, each = 2 adjacent 64B records
                    const float wzy[4] = { wz0*wy0, wz0*wy1, wz1*wy0, wz1*wy1 };
                    const int   offp[4] = { 0, YSTR*REC, ZSTR*REC, (ZSTR+YSTR)*REC };
                    const size_t base = ((size_t)z0 * ZSTR + (size_t)y0 * YSTR + x0) * REC;
                    #pragma unroll
                    for (int p = 0; p < 4; ++p) {
                        const uint4* P = (const uint4*)(rec + base + offp[p]);
                        uint4 q0[4], q1[4];
                        q0[0]=P[0]; q0[1]=P[1]; q0[2]=P[2]; q0[3]=P[3];
                        q1[0]=P[4]; q1[1]=P[5]; q1[2]=P[6]; q1[3]=P[7];
                        const float wA = wzy[p] * wx0, wB = wzy[p] * wx1;
                        #pragma unroll
                        for (int q = 0; q < 4; ++q) {
                            const unsigned* u0 = (const unsigned*)&q0[q];
                            const unsigned* u1 = (const unsigned*)&q1[q];
                            #pragma unroll
                            for (int d = 0; d < 4; ++d) {
                                const int ch = q*8 + d*2;      // channels ch, ch+1
                                if (ch >= 28) break;
                                float l0, h0, l1, h1;
                                bf2(u0[d], l0, h0);
                                bf2(u1[d], l1, h1);
                                const float vA = fmaf(l1, wB, l0 * wA);   // channel ch
                                const float vBv= fmaf(h1, wB, h0 * wA);   // channel ch+1
                                // route channel ch
                                if (ch == 0) sv += vA;
                                else {
                                    const int j = ch - 1;
                                    const float c = shv[j % 9] * vA;
                                    if (j < 9) a0 += c; else if (j < 18) a1 += c; else a2 += c;
                                }
                                // route channel ch+1
                                if (ch + 1 < 28) {
                                    const int j = ch;          // (ch+1)-1
                                    const float c = shv[j % 9] * vBv;
                                    if (j < 9) a0 += c; else if (j < 18) a1 += c; else a2 += c;
                                }
                            }
                        }
                    }
                } else {
                    // boundary: masked per-corner
                    const float vwx[2] = { (x0   >= 0 && x0   < RESN) ? wx0 : 0.f,
                                           (x0+1 >= 0 && x0+1 < RESN) ? wx1 : 0.f };
                    const float vwy[2] = { (y0   >= 0 && y0   < RESN) ? wy0 : 0.f,
                                           (y0+1 >= 0 && y0+1 < RESN) ? wy1 : 0.f };
                    const float vwz[2] = { (z0   >= 0 && z0   < RESN) ? wz0 : 0.f,
                                           (z0+1 >= 0 && z0+1 < RESN) ? wz1 : 0.f };
                    const int cx[2] = { min(max(x0,0),RESN-1), min(max(x0+1,0),RESN-1) };
                    const int cy[2] = { min(max(y0,0),RESN-1), min(max(y0+1,0),RESN-1) };
                    const int cz[2] = { min(max(z0,0),RESN-1), min(max(z0+1,0),RESN-1) };
                    for (int dz = 0; dz < 2; ++dz)
                    for (int dy = 0; dy < 2; ++dy)
                    for (int dx = 0; dx < 2; ++dx) {
                        const float w = vwz[dz]*vwy[dy]*vwx[dx];
                        if (w == 0.f) continue;
                        const uint4* P = (const uint4*)(rec +
                            ((size_t)cz[dz]*ZSTR + (size_t)cy[dy]*YSTR + cx[dx]) * REC);
                        uint4 qq[4]; qq[0]=P[0]; qq[1]=P[1]; qq[2]=P[2]; qq[3]=P[3];
                        #pragma unroll
                        for (int q = 0; q < 4; ++q) {
                            const unsigned* u = (const unsigned*)&qq[q];
                            #pragma unroll
                            for (int d = 0; d < 4; ++d) {
                                const int ch = q*8 + d*2;
                                if (ch >= 28) break;
                                float lo, hi; bf2(u[d], lo, hi);
                                if (ch == 0) sv = fmaf(lo, w, sv);
                                else {
                                    const int j = ch - 1;
                                    const float c = shv[j % 9] * lo * w;
                                    if (j < 9) a0 += c; else if (j < 18) a1 += c; else a2 += c;
                                }
                                if (ch + 1 < 28) {
                                    const int j = ch;
                                    const float c = shv[j % 9] * hi * w;
                                    if (j < 9) a0 += c; else if (j < 18) a1 += c; else a2 += c;
                                }
                            }
                        }
                    }
                }

                sv = fmaxf(sv, 0.f);
                alpha = 1.f - __expf(-sv * dist);
                cr = __fdividef(1.f, 1.f + __expf(-a0));
                cg = __fdividef(1.f, 1.f + __expf(-a1));
                cb = __fdividef(1.f, 1.f + __expf(-a2));
            }

            // wave-wide multiplicative scan
            float m = (s <= my_hi) ? (1.f - alpha + 1e-10f) : 1.f;
            float incl = m;
            #pragma unroll
            for (int off = 1; off < 64; off <<= 1) {
                float nb = __shfl_up(incl, off);
                if (lane >= off) incl *= nb;
            }
            float excl = __shfl_up(incl, 1);
            if (lane == 0) excl = 1.f;

            const float T = carry * excl;
            const float w = T * alpha;
            accR = fmaf(w, cr, accR);
            accG = fmaf(w, cg, accG);
            accB = fmaf(w, cb, accB);
            accL += w;
            carry *= __shfl(incl, 63);
        }
    }

    // intra-wave reduce
    #pragma unroll
    for (int off = 32; off; off >>= 1) {
        accR += __shfl_xor(accR, off);
        accG += __shfl_xor(accG, off);
        accB += __shfl_xor(accB, off);
        accL += __shfl_xor(accL, off);
    }

    __shared__ float sP[4], sR[4], sG[4], sB[4], sL[4];
    if (lane == 0) { sP[wave]=carry; sR[wave]=accR; sG[wave]=accG; sB[wave]=accB; sL[wave]=accL; }
    __syncthreads();
    if (tid == 0) {
        float T = 1.f, R = 0.f, G = 0.f, Bc = 0.f, L = 0.f;
        #pragma unroll
        for (int w = 0; w < 4; ++w) {
            R  += T * sR[w];
            G  += T * sG[w];
            Bc += T * sB[w];
            L  += T * sL[w];
            T  *= sP[w];
        }
        const float bg = 1.f - L;
        out[ray*3+0] = R  + bg;
        out[ray*3+1] = G  + bg;
        out[ray*3+2] = Bc + bg;
    }
}

// ===================== fallback (round-1 kernel, f32 direct) =====================
__device__ __forceinline__ float plane_interior(const float* __restrict__ p,
                                                float w00, float w01, float w10, float w11,
                                                float wx0, float wx1)
{
    f2_u a = *(const f2_u*)(p);
    f2_u b = *(const f2_u*)(p + YSTR);
    f2_u c = *(const f2_u*)(p + ZSTR);
    f2_u d = *(const f2_u*)(p + ZSTR + YSTR);
    float v0 = fmaf(a.y, wx1, a.x * wx0);
    float v1 = fmaf(b.y, wx1, b.x * wx0);
    float v2 = fmaf(c.y, wx1, c.x * wx0);
    float v3 = fmaf(d.y, wx1, d.x * wx0);
    return fmaf(v3, w11, fmaf(v2, w10, fmaf(v1, w01, v0 * w00)));
}

__global__ __launch_bounds__(64)
void plenoxel_render_f32(const float* __restrict__ rays_o,
                         const float* __restrict__ rays_d,
                         const float* __restrict__ sig,
                         const float* __restrict__ rgb,
                         float* __restrict__ out)
{
    const int ray  = blockIdx.x;
    const int lane = threadIdx.x;
    const float ox = rays_o[ray*3+0], oy = rays_o[ray*3+1], oz = rays_o[ray*3+2];
    const float dxr = rays_d[ray*3+0], dyr = rays_d[ray*3+1], dzr = rays_d[ray*3+2];
    const float h = 2.6f * 1.7320508075688772f / 480.0f;
    const float ax = (1.3f - ox) / dxr, bx = (-1.3f - ox) / dxr;
    const float ay = (1.3f - oy) / dyr, by = (-1.3f - oy) / dyr;
    const float az = (1.3f - oz) / dzr, bz = (-1.3f - oz) / dzr;
    float start = fmaxf(fmaxf(fminf(ax, bx), fminf(ay, by)), fminf(az, bz));
    start = fminf(fmaxf(start, 0.2f), 6.0f);
    const float B = 1.3164f;
    const float mx1 = ( B - ox) / dxr, mx0 = (-B - ox) / dxr;
    const float my1 = ( B - oy) / dyr, my0 = (-B - oy) / dyr;
    const float mz1 = ( B - oz) / dzr, mz0 = (-B - oz) / dzr;
    float tl = fmaxf(fmaxf(fminf(mx0, mx1), fminf(my0, my1)), fminf(mz0, mz1));
    float th = fminf(fminf(fmaxf(mx0, mx1), fmaxf(my0, my1)), fmaxf(mz0, mz1));
    tl = fmaxf(tl, start);
    th = fminf(th, fmaf((float)NPTS, h, start));
    int s_lo, s_hi;
    if (th < tl) { s_lo = 0; s_hi = -1; }
    else {
        s_lo = max(0,    (int)floorf((tl - start) / h) - 1);
        s_hi = min(NPTS, (int)ceilf ((th - start) / h) + 1);
    }
    const float dsq  = dxr*dxr + dyr*dyr + dzr*dzr;
    const float dinv = rsqrtf(dsq);
    const float dn   = sqrtf(dsq);
    const float X = dxr * dinv, Y = dyr * dinv, Z = dzr * dinv;
    const float shv[9] = {
        0.28209479177387814f, -0.4886025119029199f * Y, 0.4886025119029199f * Z,
        -0.4886025119029199f * X, 1.0925484305920792f * X * Y, -1.0925484305920792f * Y * Z,
        0.31539156525252005f * (2.0f * Z * Z - X * X - Y * Y),
        -1.0925484305920792f * X * Z, 0.5462742152960396f * (X * X - Y * Y),
    };
    const float dist = h * dn;
    float accR = 0.f, accG = 0.f, accB = 0.f, accL = 0.f;
    float carry = 1.0f;
    for (int basei = s_lo; basei <= s_hi; basei += 64) {
        const int s = basei + lane;
        float alpha = 0.f, cr = 0.f, cg = 0.f, cb = 0.f;
        if (s <= s_hi) {
            const float t  = fmaf((float)s, h, start);
            const float px = fmaf(dxr, t, ox);
            const float py = fmaf(dyr, t, oy);
            const float pz = fmaf(dzr, t, oz);
            const float fx = fmaf(px, 61.153846153846f, 79.5f);
            const float fy = fmaf(py, 61.153846153846f, 79.5f);
            const float fz = fmaf(pz, 61.153846153846f, 79.5f);
            const float fxf = floorf(fx), fyf = floorf(fy), fzf = floorf(fz);
            const int   x0 = (int)fxf, y0 = (int)fyf, z0 = (int)fzf;
            const float wx1 = fx - fxf, wy1 = fy - fyf, wz1 = fz - fzf;
            const float wx0 = 1.f - wx1, wy0 = 1.f - wy1, wz0 = 1.f - wz1;
            float sv = 0.f, a0 = 0.f, a1 = 0.f, a2 = 0.f;
            if (x0 >= 0 && x0 <= 158 && y0 >= 0 && y0 <= 158 && z0 >= 0 && z0 <= 158) {
                const float w00 = wz0*wy0, w01 = wz0*wy1, w10 = wz1*wy0, w11 = wz1*wy1;
                const size_t bofs = (size_t)z0 * ZSTR + (size_t)y0 * YSTR + (size_t)x0;
                sv = plane_interior(sig + bofs, w00, w01, w10, w11, wx0, wx1);
                const float* rp = rgb + bofs;
                #pragma unroll
                for (int c = 0; c < 3; ++c) {
                    float sc = 0.f;
                    #pragma unroll
                    for (int k = 0; k < 9; ++k) {
                        const float v = plane_interior(rp + (size_t)(c*9+k)*VOX,
                                                       w00, w01, w10, w11, wx0, wx1);
                        sc = fmaf(v, shv[k], sc);
                    }
                    if (c == 0) a0 = sc; else if (c == 1) a1 = sc; else a2 = sc;
                }
            } else {
                const float vwx0 = (x0   >= 0 && x0   < RESN) ? wx0 : 0.f;
                const float vwx1 = (x0+1 >= 0 && x0+1 < RESN) ? wx1 : 0.f;
                const float vwy0 = (y0   >= 0 && y0   < RESN) ? wy0 : 0.f;
                const float vwy1 = (y0+1 >= 0 && y0+1 < RESN) ? wy1 : 0.f;
                const float vwz0 = (z0   >= 0 && z0   < RESN) ? wz0 : 0.f;
                const float vwz1 = (z0+1 >= 0 && z0+1 < RESN) ? wz1 : 0.f;
                const int cx0 = min(max(x0,   0), RESN-1), cx1 = min(max(x0+1, 0), RESN-1);
                const int cy0 = min(max(y0,   0), RESN-1), cy1 = min(max(y0+1, 0), RESN-1);
                const int cz0 = min(max(z0,   0), RESN-1), cz1 = min(max(z0+1, 0), RESN-1);
                const float cw[8] = { vwz0*vwy0*vwx0, vwz0*vwy0*vwx1,
                                      vwz0*vwy1*vwx0, vwz0*vwy1*vwx1,
                                      vwz1*vwy0*vwx0, vwz1*vwy0*vwx1,
                                      vwz1*vwy1*vwx0, vwz1*vwy1*vwx1 };
                const size_t co[8] = {
                    (size_t)cz0*ZSTR + (size_t)cy0*YSTR + cx0,
                    (size_t)cz0*ZSTR + (size_t)cy0*YSTR + cx1,
                    (size_t)cz0*ZSTR + (size_t)cy1*YSTR + cx0,
                    (size_t)cz0*ZSTR + (size_t)cy1*YSTR + cx1,
                    (size_t)cz1*ZSTR + (size_t)cy0*YSTR + cx0,
                    (size_t)cz1*ZSTR + (size_t)cy0*YSTR + cx1,
                    (size_t)cz1*ZSTR + (size_t)cy1*YSTR + cx0,
                    (size_t)cz1*ZSTR + (size_t)cy1*YSTR + cx1 };
                #pragma unroll
                for (int j = 0; j < 8; ++j) {
                    if (cw[j] != 0.f) {
                        const float wj = cw[j];
                        sv = fmaf(sig[co[j]], wj, sv);
                        const float* rp = rgb + co[j];
                        float t0 = 0.f, t1 = 0.f, t2 = 0.f;
                        #pragma unroll
                        for (int k = 0; k < 9; ++k) {
                            t0 = fmaf(rp[(size_t)(k     )*VOX], shv[k], t0);
                            t1 = fmaf(rp[(size_t)(k +  9)*VOX], shv[k], t1);
                            t2 = fmaf(rp[(size_t)(k + 18)*VOX], shv[k], t2);
                        }
                        a0 = fmaf(t0, wj, a0);
                        a1 = fmaf(t1, wj, a1);
                        a2 = fmaf(t2, wj, a2);
                    }
                }
            }
            sv = fmaxf(sv, 0.f);
            alpha = 1.f - __expf(-sv * dist);
            cr = __fdividef(1.f, 1.f + __expf(-a0));
            cg = __fdividef(1.f, 1.f + __expf(-a1));
            cb = __fdividef(1.f, 1.f + __expf(-a2));
        }
        float m = (s <= s_hi) ? (1.f - alpha + 1e-10f) : 1.f;
        float incl = m;
        #pragma unroll
        for (int off = 1; off < 64; off <<= 1) {
            float nb = __shfl_up(incl, off);
            if (lane >= off) incl *= nb;
        }
        float excl = __shfl_up(incl, 1);
        if (lane == 0) excl = 1.f;
        const float T = carry * excl;
        const float w = T * alpha;
        accR = fmaf(w, cr, accR);
        accG = fmaf(w, cg, accG);
        accB = fmaf(w, cb, accB);
        accL += w;
        carry *= __shfl(incl, 63);
    }
    #pragma unroll
    for (int off = 32; off; off >>= 1) {
        accR += __shfl_xor(accR, off);
        accG += __shfl_xor(accG, off);
        accB += __shfl_xor(accB, off);
        accL += __shfl_xor(accL, off);
    }
    if (lane == 0) {
        const float bg = 1.f - accL;
        out[ray*3+0] = accR + bg;
        out[ray*3+1] = accG + bg;
        out[ray*3+2] = accB + bg;
    }
}

extern "C" void kernel_launch(void* const* d_in, const int* in_sizes, int n_in,
                              void* d_out, int out_size, void* d_ws, size_t ws_size,
                              hipStream_t stream) {
    const float* rays_o = (const float*)d_in[0];
    const float* rays_d = (const float*)d_in[1];
    const float* sig    = (const float*)d_in[2];
    const float* rgb    = (const float*)d_in[3];
    float* out = (float*)d_out;

    const size_t need = (size_t)VOX * REC * sizeof(unsigned short);  // 262,144,000 B
    if (ws_size >= need) {
        unsigned short* rec = (unsigned short*)d_ws;
        transpose_grid<<<VOX / 256, 256, 0, stream>>>(sig, rgb, rec);
        plenoxel_render2<<<NRAYS, 256, 0, stream>>>(rays_o, rays_d, rec, out);
    } else {
        plenoxel_render_f32<<<NRAYS, 64, 0, stream>>>(rays_o, rays_d, sig, rgb, out);
    }
}